// Round 3
// baseline (582.040 us; speedup 1.0000x reference)
//
#include <hip/hip_runtime.h>
#include <hip/hip_cooperative_groups.h>

namespace cg = cooperative_groups;

#define NROW 512
#define NCOL 65536
#define NTHR 512

// Single cooperative kernel, no K materialization (K = exp(-20*M) recomputed
// per pass; M is L3-resident after pass 1, so passes are L3-BW bound, and we
// never write 67 MB of Kh to HBM).
//
//  pass1 : t0 = colsum(exp(-20M)); v1 = b/(t0/512 + eps)
//  loop  : rowdot u_k = a/(K v_k + eps)
//          [cpt==100 -> dedicated loss pass, break]
//          colsum t = K^T u_k  (+ fused err & SPECULATIVE loss when cpt%50==1)
//          err<=thr -> break (loss already computed in this pass)
//          v_{k+1} = b/(t + eps)
//  tail  : block 0 reduces per-block loss partials -> out
//
// Reference-semantics alignment: at iteration k, v holds v_k entering rowdot;
// err at k in {1,51} uses (v_k, K^T u_k); breaks keep (u_k, v_k).
template<int NB>
__global__ __launch_bounds__(NTHR, 8)
void sinkhorn(const float* __restrict__ M, float* __restrict__ out,
              float* __restrict__ v, float* __restrict__ rPart,
              float* __restrict__ lossPart, float* __restrict__ errAcc)
{
  constexpr int CPB   = NCOL / NB;   // cols per block (col-major passes)
  constexpr int CHK   = CPB / 4;     // float4 chunks per block
  constexpr int PARTS = NTHR / CHK;  // row partitions
  constexpr int RPP   = NROW / PARTS;// rows per partition
  constexpr int SPLIT = NB / NROW;   // blocks per row (rowdot)
  constexpr int NW    = NTHR / 64;   // waves per block

  cg::grid_group grid = cg::this_grid();
  const int tid = threadIdx.x;
  const int bid = blockIdx.x;

  const float am = 1.0f / NROW, bm = 1.0f / NCOL, EPSV = 1e-16f;

  __shared__ float sCol[PARTS * CPB];  // 8 KB
  __shared__ float sU[NROW];           // 2 KB
  __shared__ float sRed[NW];

  const int chunk = tid % CHK;
  const int part  = tid / CHK;
  const int col0  = bid * CPB + chunk * 4;
  const int r0    = part * RPP;

  // ---------------- pass 1: colsum -> v1 ----------------
  {
    float4 cs = {0.f, 0.f, 0.f, 0.f};
    #pragma unroll 4
    for (int r = r0; r < r0 + RPP; ++r) {
      float4 m = *(const float4*)(M + (size_t)r * NCOL + col0);
      cs.x += __expf(-20.f * m.x);
      cs.y += __expf(-20.f * m.y);
      cs.z += __expf(-20.f * m.z);
      cs.w += __expf(-20.f * m.w);
    }
    *(float4*)(sCol + part * CPB + chunk * 4) = cs;
    if (bid == 0 && tid < 2) errAcc[tid] = 0.f;
    __syncthreads();
    if (tid < CPB) {
      float t = 0.f;
      #pragma unroll
      for (int p = 0; p < PARTS; ++p) t += sCol[p * CPB + tid];
      v[bid * CPB + tid] = bm / (t * am + EPSV);  // v1 = b/(K^T u0 + eps)
    }
  }
  grid.sync();

  // ---------------- Sinkhorn loop ----------------
  int cpt = 0, errIdx = 0;
  while (true) {
    // rowdot: u_k = a / (K v_k + eps)
    {
      const int row  = bid / SPLIT;
      const int half = bid % SPLIT;
      const float4* M4 = (const float4*)M + (size_t)row * (NCOL / 4)
                         + (size_t)half * (NCOL / 4 / SPLIT);
      const float4* V4 = (const float4*)v + (size_t)half * (NCOL / 4 / SPLIT);
      constexpr int ITER = NCOL / 4 / SPLIT / NTHR;
      float acc = 0.f;
      #pragma unroll 4
      for (int it = 0; it < ITER; ++it) {
        const int c = it * NTHR + tid;
        float4 m = M4[c];
        float4 vv = V4[c];
        acc += __expf(-20.f * m.x) * vv.x + __expf(-20.f * m.y) * vv.y
             + __expf(-20.f * m.z) * vv.z + __expf(-20.f * m.w) * vv.w;
      }
      #pragma unroll
      for (int off = 32; off; off >>= 1) acc += __shfl_down(acc, off, 64);
      if ((tid & 63) == 0) sRed[tid >> 6] = acc;
      __syncthreads();
      if (tid == 0) {
        float s = 0.f;
        #pragma unroll
        for (int w = 0; w < NW; ++w) s += sRed[w];
        rPart[bid] = s;
      }
    }
    grid.sync();
    cpt++;

    if (cpt >= 100) {
      // dedicated loss pass (u_100 from rPart, v = v_100)
      {
        float s = 0.f;
        #pragma unroll
        for (int h = 0; h < SPLIT; ++h) s += rPart[tid * SPLIT + h];
        sU[tid] = am / (s + EPSV);
      }
      __syncthreads();
      float4 vv = *(const float4*)(v + col0);
      float lacc = 0.f;
      #pragma unroll 4
      for (int r = r0; r < r0 + RPP; ++r) {
        float4 m = *(const float4*)(M + (size_t)r * NCOL + col0);
        float us = sU[r];
        lacc += us * (__expf(-20.f * m.x) * vv.x * m.x
                    + __expf(-20.f * m.y) * vv.y * m.y
                    + __expf(-20.f * m.z) * vv.z * m.z
                    + __expf(-20.f * m.w) * vv.w * m.w);
      }
      #pragma unroll
      for (int off = 32; off; off >>= 1) lacc += __shfl_down(lacc, off, 64);
      if ((tid & 63) == 0) sRed[tid >> 6] = lacc;
      __syncthreads();
      if (tid == 0) {
        float s = 0.f;
        #pragma unroll
        for (int w = 0; w < NW; ++w) s += sRed[w];
        lossPart[bid] = s;
      }
      grid.sync();
      break;
    }

    const bool pending = ((cpt % 50) == 1);  // err checks at cpt==1, 51

    // colsum t = K^T u_k  (+ fused err & speculative loss when pending)
    {
      float s = 0.f;
      #pragma unroll
      for (int h = 0; h < SPLIT; ++h) s += rPart[tid * SPLIT + h];
      sU[tid] = am / (s + EPSV);
    }
    __syncthreads();
    float4 cs = {0.f, 0.f, 0.f, 0.f};
    float lacc = 0.f;
    float4 vv = {0.f, 0.f, 0.f, 0.f};
    if (pending) vv = *(const float4*)(v + col0);
    #pragma unroll 4
    for (int r = r0; r < r0 + RPP; ++r) {
      float4 m = *(const float4*)(M + (size_t)r * NCOL + col0);
      float e0 = __expf(-20.f * m.x), e1 = __expf(-20.f * m.y);
      float e2 = __expf(-20.f * m.z), e3 = __expf(-20.f * m.w);
      float us = sU[r];
      cs.x = fmaf(e0, us, cs.x);
      cs.y = fmaf(e1, us, cs.y);
      cs.z = fmaf(e2, us, cs.z);
      cs.w = fmaf(e3, us, cs.w);
      if (pending)
        lacc += us * (e0 * vv.x * m.x + e1 * vv.y * m.y
                    + e2 * vv.z * m.z + e3 * vv.w * m.w);
    }
    *(float4*)(sCol + part * CPB + chunk * 4) = cs;
    __syncthreads();
    float t = 0.f;
    if (tid < CPB) {
      #pragma unroll
      for (int p = 0; p < PARTS; ++p) t += sCol[p * CPB + tid];
    }

    if (pending) {
      // speculative loss partial for this block
      #pragma unroll
      for (int off = 32; off; off >>= 1) lacc += __shfl_down(lacc, off, 64);
      if ((tid & 63) == 0) sRed[tid >> 6] = lacc;
      __syncthreads();
      if (tid == 0) {
        float s = 0.f;
        #pragma unroll
        for (int w = 0; w < NW; ++w) s += sRed[w];
        lossPart[bid] = s;
      }
      __syncthreads();
      // err = sum_j |v_j * t_j - b|
      float pe = (tid < CPB) ? fabsf(v[bid * CPB + tid] * t - bm) : 0.f;
      #pragma unroll
      for (int off = 32; off; off >>= 1) pe += __shfl_down(pe, off, 64);
      if ((tid & 63) == 0) sRed[tid >> 6] = pe;
      __syncthreads();
      if (tid == 0) {
        float s = 0.f;
        #pragma unroll
        for (int w = 0; w < NW; ++w) s += sRed[w];
        atomicAdd(&errAcc[errIdx], s);
      }
      grid.sync();
      float err = errAcc[errIdx];
      errIdx++;
      if (err <= 0.005f) break;  // keep u_k, v_k; lossPart already valid
    }

    if (tid < CPB) v[bid * CPB + tid] = bm / (t + EPSV);
    grid.sync();
  }

  // ---------------- tail: block 0 reduces loss partials ----------------
  if (bid == 0) {
    float s = 0.f;
    for (int i = tid; i < NB; i += NTHR) s += lossPart[i];
    #pragma unroll
    for (int off = 32; off; off >>= 1) s += __shfl_down(s, off, 64);
    if ((tid & 63) == 0) sRed[tid >> 6] = s;
    __syncthreads();
    if (tid == 0) {
      float tot = 0.f;
      #pragma unroll
      for (int w = 0; w < NW; ++w) tot += sRed[w];
      out[0] = 100.f * tot;
    }
  }
}

extern "C" void kernel_launch(void* const* d_in, const int* in_sizes, int n_in,
                              void* d_out, int out_size, void* d_ws, size_t ws_size,
                              hipStream_t stream) {
  const float* M = (const float*)d_in[0];
  float* out = (float*)d_out;

  // workspace layout (tiny): v | rPart | lossPart | errAcc
  const size_t offV = 0;
  const size_t offR = offV + (size_t)NCOL * sizeof(float);   // 256 KB
  const size_t offL = offR + 4096;                            // rPart (<=1024 f)
  const size_t offE = offL + 4096;                            // lossPart
  const size_t need = offE + 256;
  if (ws_size < need) return;

  char* ws = (char*)d_ws;
  float* v  = (float*)(ws + offV);
  float* rP = (float*)(ws + offR);
  float* lP = (float*)(ws + offL);
  float* eA = (float*)(ws + offE);

  void* args[] = { (void*)&M, (void*)&out, (void*)&v, (void*)&rP, (void*)&lP, (void*)&eA };

  // primary: 1024 blocks (4/CU @ 32 waves/CU); fallback: 512 blocks (2/CU)
  hipError_t e = hipLaunchCooperativeKernel((void*)sinkhorn<1024>, dim3(1024),
                                            dim3(NTHR), args, 0, stream);
  if (e != hipSuccess) {
    hipLaunchCooperativeKernel((void*)sinkhorn<512>, dim3(512),
                               dim3(NTHR), args, 0, stream);
  }
}

// Round 4
// 274.614 us; speedup vs baseline: 2.1195x; 2.1195x over previous
//
#include <hip/hip_runtime.h>
#include <hip/hip_cooperative_groups.h>

namespace cg = cooperative_groups;

#define NROW 512
#define NCOL 65536

static __device__ __forceinline__ float wave_sum(float x) {
  #pragma unroll
  for (int off = 32; off; off >>= 1) x += __shfl_down(x, off, 64);
  return x;
}

// ---------------- K1: v1 = b / (colsum(exp(-20M))/512 + eps) ----------------
// 1024 blocks x 256 thr; block owns 64 cols x all 512 rows. Also zeros eA.
__global__ __launch_bounds__(256)
void k1_colsum(const float* __restrict__ M, float* __restrict__ v,
               float* __restrict__ eA) {
  const int tid = threadIdx.x, bid = blockIdx.x;
  const int chunk = tid & 15;          // 16 float4 chunks = 64 cols
  const int part  = tid >> 4;          // 16 parts x 32 rows
  const int col0  = (bid << 6) + (chunk << 2);
  const int r0    = part << 5;
  const float am = 1.0f / NROW, bm = 1.0f / NCOL, EPSV = 1e-16f;

  __shared__ float sCol[16 * 64];

  if (bid == 0 && tid < 3) eA[tid] = 0.f;   // eA[0]=err1, eA[1]=err51, eA[2]=loss

  float4 cs = {0.f, 0.f, 0.f, 0.f};
  #pragma unroll 8
  for (int r = r0; r < r0 + 32; ++r) {
    float4 m = *(const float4*)(M + (size_t)r * NCOL + col0);
    cs.x += __expf(-20.f * m.x);
    cs.y += __expf(-20.f * m.y);
    cs.z += __expf(-20.f * m.z);
    cs.w += __expf(-20.f * m.w);
  }
  *(float4*)(sCol + part * 64 + (chunk << 2)) = cs;
  __syncthreads();
  if (tid < 64) {
    float t = 0.f;
    #pragma unroll
    for (int p = 0; p < 16; ++p) t += sCol[p * 64 + tid];
    v[(bid << 6) + tid] = bm / (t * am + EPSV);
  }
}

// ---------------- K2: u1[row] = a / (sum_j exp(-20M[row,j]) v[j] + eps) -----
// 512 blocks x 256 thr; one row per block, fully contiguous reads.
__global__ __launch_bounds__(256)
void k2_rowdot(const float* __restrict__ M, const float* __restrict__ v,
               float* __restrict__ u) {
  const int tid = threadIdx.x, row = blockIdx.x;
  const float am = 1.0f / NROW, EPSV = 1e-16f;
  const float4* M4 = (const float4*)M + (size_t)row * (NCOL / 4);
  const float4* V4 = (const float4*)v;
  __shared__ float sRed[4];

  float acc = 0.f;
  #pragma unroll 8
  for (int it = 0; it < NCOL / 4 / 256; ++it) {   // 64 iters
    const int c = (it << 8) + tid;
    float4 m = M4[c];
    float4 vv = V4[c];
    acc += __expf(-20.f * m.x) * vv.x + __expf(-20.f * m.y) * vv.y
         + __expf(-20.f * m.z) * vv.z + __expf(-20.f * m.w) * vv.w;
  }
  acc = wave_sum(acc);
  if ((tid & 63) == 0) sRed[tid >> 6] = acc;
  __syncthreads();
  if (tid == 0)
    u[row] = am / (sRed[0] + sRed[1] + sRed[2] + sRed[3] + EPSV);
}

// ---------------- K3: t = K^T u1 (stored), err partial, speculative loss ----
// 1024 blocks x 256 thr, same slab geometry as K1.
__global__ __launch_bounds__(256)
void k3_fused(const float* __restrict__ M, const float* __restrict__ v,
              const float* __restrict__ u, float* __restrict__ tArr,
              float* __restrict__ eA) {
  const int tid = threadIdx.x, bid = blockIdx.x;
  const int chunk = tid & 15;
  const int part  = tid >> 4;
  const int col0  = (bid << 6) + (chunk << 2);
  const int r0    = part << 5;
  const float bm = 1.0f / NCOL;

  __shared__ float sU[NROW];
  __shared__ float sCol[16 * 64];
  __shared__ float sRed[4];

  sU[tid] = u[tid];
  sU[tid + 256] = u[tid + 256];
  __syncthreads();

  const float4 vv = *(const float4*)(v + col0);
  float4 cs = {0.f, 0.f, 0.f, 0.f};
  float lacc = 0.f;
  #pragma unroll 8
  for (int r = r0; r < r0 + 32; ++r) {
    float4 m = *(const float4*)(M + (size_t)r * NCOL + col0);
    float e0 = __expf(-20.f * m.x), e1 = __expf(-20.f * m.y);
    float e2 = __expf(-20.f * m.z), e3 = __expf(-20.f * m.w);
    float us = sU[r];
    cs.x = fmaf(e0, us, cs.x);
    cs.y = fmaf(e1, us, cs.y);
    cs.z = fmaf(e2, us, cs.z);
    cs.w = fmaf(e3, us, cs.w);
    lacc += us * (e0 * m.x * vv.x + e1 * m.y * vv.y
                + e2 * m.z * vv.z + e3 * m.w * vv.w);
  }
  *(float4*)(sCol + part * 64 + (chunk << 2)) = cs;
  lacc = wave_sum(lacc);
  if ((tid & 63) == 0) sRed[tid >> 6] = lacc;
  __syncthreads();

  float pe = 0.f;
  if (tid < 64) {
    float t = 0.f;
    #pragma unroll
    for (int p = 0; p < 16; ++p) t += sCol[p * 64 + tid];
    tArr[(bid << 6) + tid] = t;
    pe = fabsf(v[(bid << 6) + tid] * t - bm);
    pe = wave_sum(pe);
  }
  if (tid == 0) {
    atomicAdd(&eA[0], pe);
    atomicAdd(&eA[2], sRed[0] + sRed[1] + sRed[2] + sRed[3]);
  }
}

// ---------------- K4: decide ----------------
__global__ void k4_decide(const float* __restrict__ eA, float* __restrict__ out,
                          int* __restrict__ done) {
  if (threadIdx.x == 0) {
    if (eA[0] <= 0.005f) { out[0] = 100.f * eA[2]; done[0] = 1; }
    else                 { out[0] = 0.f;           done[0] = 0; }
  }
}

// ---------------- K5: cooperative fallback (iters 2..100 + loss) ------------
// 256 blocks x 1024 thr (cheap-sync geometry). Exits immediately when done.
__global__ __launch_bounds__(1024)
void k5_fallback(const float* __restrict__ M, float* __restrict__ out,
                 float* __restrict__ v, float* __restrict__ u,
                 const float* __restrict__ tArr, float* __restrict__ eA,
                 const int* __restrict__ done) {
  if (done[0]) return;
  cg::grid_group grid = cg::this_grid();
  const int tid = threadIdx.x, bid = blockIdx.x;
  const float am = 1.0f / NROW, bm = 1.0f / NCOL, EPSV = 1e-16f;

  __shared__ float sU[NROW];
  __shared__ float sCol[16 * 256];   // 16 KB
  __shared__ float sRedA[16], sRedB[16];

  const int chunk = tid & 63;        // 64 float4 chunks = 256 cols
  const int part  = tid >> 6;        // 16 parts x 32 rows
  const int col0  = (bid << 8) + (chunk << 2);
  const int r0    = part << 5;
  const int row0  = bid << 1;

  float tt = (tid < 256) ? tArr[(bid << 8) + tid] : 0.f;

  int cpt = 1;
  while (true) {
    // v_{cpt+1} = b / (tt + eps)
    if (tid < 256) v[(bid << 8) + tid] = bm / (tt + EPSV);
    grid.sync();
    cpt++;

    // rowdot: u_cpt for rows row0, row0+1
    {
      const float4* M40 = (const float4*)M + (size_t)row0 * (NCOL / 4);
      const float4* M41 = (const float4*)M + (size_t)(row0 + 1) * (NCOL / 4);
      const float4* V4  = (const float4*)v;
      float ra = 0.f, rb = 0.f;
      #pragma unroll 4
      for (int it = 0; it < NCOL / 4 / 1024; ++it) {  // 16 iters
        const int c = (it << 10) + tid;
        float4 vv = V4[c];
        float4 m0 = M40[c], m1 = M41[c];
        ra += __expf(-20.f * m0.x) * vv.x + __expf(-20.f * m0.y) * vv.y
            + __expf(-20.f * m0.z) * vv.z + __expf(-20.f * m0.w) * vv.w;
        rb += __expf(-20.f * m1.x) * vv.x + __expf(-20.f * m1.y) * vv.y
            + __expf(-20.f * m1.z) * vv.z + __expf(-20.f * m1.w) * vv.w;
      }
      ra = wave_sum(ra); rb = wave_sum(rb);
      if ((tid & 63) == 0) { sRedA[tid >> 6] = ra; sRedB[tid >> 6] = rb; }
      __syncthreads();
      if (tid < 2) {
        const float* sr = (tid == 0) ? sRedA : sRedB;
        float s = 0.f;
        #pragma unroll
        for (int w = 0; w < 16; ++w) s += sr[w];
        u[row0 + tid] = am / (s + EPSV);
      }
    }
    grid.sync();
    if (cpt >= 100) break;

    // colsum: tt = (K^T u_cpt) for my 256 cols
    if (tid < NROW) sU[tid] = u[tid];
    __syncthreads();
    float4 cs = {0.f, 0.f, 0.f, 0.f};
    #pragma unroll 4
    for (int r = r0; r < r0 + 32; ++r) {
      float4 m = *(const float4*)(M + (size_t)r * NCOL + col0);
      float us = sU[r];
      cs.x = fmaf(__expf(-20.f * m.x), us, cs.x);
      cs.y = fmaf(__expf(-20.f * m.y), us, cs.y);
      cs.z = fmaf(__expf(-20.f * m.z), us, cs.z);
      cs.w = fmaf(__expf(-20.f * m.w), us, cs.w);
    }
    *(float4*)(sCol + part * 256 + (chunk << 2)) = cs;
    __syncthreads();
    if (tid < 256) {
      tt = 0.f;
      #pragma unroll
      for (int p = 0; p < 16; ++p) tt += sCol[p * 256 + tid];
    }

    if (cpt == 51) {
      float pe = (tid < 256) ? fabsf(v[(bid << 8) + tid] * tt - bm) : 0.f;
      pe = wave_sum(pe);
      __syncthreads();
      if ((tid & 63) == 0) sRedA[tid >> 6] = pe;
      __syncthreads();
      if (tid == 0) {
        float s = 0.f;
        #pragma unroll
        for (int w = 0; w < 16; ++w) s += sRedA[w];
        atomicAdd(&eA[1], s);
      }
      grid.sync();
      if (eA[1] <= 0.005f) break;   // keep u_51, v_51
    }
  }

  // loss = 100 * sum(u_i exp(-20 M_ij) v_j M_ij); out was zeroed by K4
  __syncthreads();
  if (tid < NROW) sU[tid] = u[tid];
  __syncthreads();
  {
    const float4 vv = *(const float4*)(v + col0);
    float lacc = 0.f;
    #pragma unroll 4
    for (int r = r0; r < r0 + 32; ++r) {
      float4 m = *(const float4*)(M + (size_t)r * NCOL + col0);
      float us = sU[r];
      lacc += us * (__expf(-20.f * m.x) * m.x * vv.x
                  + __expf(-20.f * m.y) * m.y * vv.y
                  + __expf(-20.f * m.z) * m.z * vv.z
                  + __expf(-20.f * m.w) * m.w * vv.w);
    }
    lacc = wave_sum(lacc);
    if ((tid & 63) == 0) sRedA[tid >> 6] = lacc;
    __syncthreads();
    if (tid == 0) {
      float s = 0.f;
      #pragma unroll
      for (int w = 0; w < 16; ++w) s += sRedA[w];
      atomicAdd(out, 100.f * s);
    }
  }
}

extern "C" void kernel_launch(void* const* d_in, const int* in_sizes, int n_in,
                              void* d_out, int out_size, void* d_ws, size_t ws_size,
                              hipStream_t stream) {
  const float* M = (const float*)d_in[0];
  float* out = (float*)d_out;

  // ws layout: v | tArr | u | eA | done
  const size_t offV = 0;
  const size_t offT = offV + (size_t)NCOL * sizeof(float);   // 256 KB
  const size_t offU = offT + (size_t)NCOL * sizeof(float);   // 256 KB
  const size_t offE = offU + 4096;
  const size_t offD = offE + 256;
  const size_t need = offD + 256;
  if (ws_size < need) return;

  char* ws = (char*)d_ws;
  float* v    = (float*)(ws + offV);
  float* tArr = (float*)(ws + offT);
  float* u    = (float*)(ws + offU);
  float* eA   = (float*)(ws + offE);
  int*   done = (int*)(ws + offD);

  k1_colsum<<<dim3(1024), dim3(256), 0, stream>>>(M, v, eA);
  k2_rowdot<<<dim3(512),  dim3(256), 0, stream>>>(M, v, u);
  k3_fused <<<dim3(1024), dim3(256), 0, stream>>>(M, v, u, tArr, eA);
  k4_decide<<<dim3(1),    dim3(64),  0, stream>>>(eA, out, done);

  void* args[] = { (void*)&M, (void*)&out, (void*)&v, (void*)&u,
                   (void*)&tArr, (void*)&eA, (void*)&done };
  hipLaunchCooperativeKernel((void*)k5_fallback, dim3(256), dim3(1024),
                             args, 0, stream);
}

// Round 5
// 272.806 us; speedup vs baseline: 2.1335x; 1.0066x over previous
//
#include <hip/hip_runtime.h>
#include <hip/hip_cooperative_groups.h>

namespace cg = cooperative_groups;

#define NROW 512
#define NCOL 65536
#define BANDS 8            // row bands for streaming colsum passes
#define BPB   128          // col-blocks per band (512 cols each)

static __device__ __forceinline__ float wave_sum(float x) {
  #pragma unroll
  for (int off = 32; off; off >>= 1) x += __shfl_down(x, off, 64);
  return x;
}

// ---- k1a: streaming partial colsums of E = exp(-20M) -----------------------
// 1024 blocks x 256 thr. Block (band, blk): rows [band*64, band*64+64),
// cols [blk*512, blk*512+512). Per row visit: 2 KB contiguous (page-friendly).
__global__ __launch_bounds__(256)
void k1a_partial(const float* __restrict__ M, float* __restrict__ tPart,
                 float* __restrict__ eA) {
  const int tid = threadIdx.x, bid = blockIdx.x;
  const int band = bid >> 7, blk = bid & 127;
  const int chunk = tid & 127;          // 128 float4 chunks = 512 cols
  const int part  = tid >> 7;           // 2 parts x 32 rows
  const int col0  = (blk << 9) + (chunk << 2);
  const int r0    = (band << 6) + (part << 5);

  __shared__ float sCol[2 * 512];

  if (bid == 0 && tid < 3) eA[tid] = 0.f;  // [0]=err1, [1]=err51, [2]=loss

  float4 cs = {0.f, 0.f, 0.f, 0.f};
  #pragma unroll 8
  for (int r = r0; r < r0 + 32; ++r) {
    float4 m = *(const float4*)(M + (size_t)r * NCOL + col0);
    cs.x += __expf(-20.f * m.x);
    cs.y += __expf(-20.f * m.y);
    cs.z += __expf(-20.f * m.z);
    cs.w += __expf(-20.f * m.w);
  }
  *(float4*)(sCol + part * 512 + (chunk << 2)) = cs;
  __syncthreads();
  if (tid < 128) {
    float4 a = *(const float4*)(sCol + (tid << 2));
    float4 b = *(const float4*)(sCol + 512 + (tid << 2));
    float4 t = {a.x + b.x, a.y + b.y, a.z + b.z, a.w + b.w};
    *(float4*)(tPart + (size_t)band * NCOL + (blk << 9) + (tid << 2)) = t;
  }
}

// ---- k1b: v1 = b / (colsum/512 + eps) --------------------------------------
// 64 blocks x 256 thr, 4 cols/thread.
__global__ __launch_bounds__(256)
void k1b_v1(const float* __restrict__ tPart, float* __restrict__ v) {
  const int gid = blockIdx.x * 256 + threadIdx.x;
  const int col0 = gid << 2;
  const float am = 1.0f / NROW, bm = 1.0f / NCOL, EPSV = 1e-16f;
  float4 t = {0.f, 0.f, 0.f, 0.f};
  #pragma unroll
  for (int b = 0; b < BANDS; ++b) {
    float4 p = *(const float4*)(tPart + (size_t)b * NCOL + col0);
    t.x += p.x; t.y += p.y; t.z += p.z; t.w += p.w;
  }
  float4 vv = {bm / (t.x * am + EPSV), bm / (t.y * am + EPSV),
               bm / (t.z * am + EPSV), bm / (t.w * am + EPSV)};
  *(float4*)(v + col0) = vv;
}

// ---- k2: u1[row] = a / (E[row,:] . v + eps) --------------------------------
// 512 blocks x 256 thr; one contiguous row per block.
__global__ __launch_bounds__(256)
void k2_rowdot(const float* __restrict__ M, const float* __restrict__ v,
               float* __restrict__ u) {
  const int tid = threadIdx.x, row = blockIdx.x;
  const float am = 1.0f / NROW, EPSV = 1e-16f;
  const float4* M4 = (const float4*)M + (size_t)row * (NCOL / 4);
  const float4* V4 = (const float4*)v;
  __shared__ float sRed[4];

  float acc = 0.f;
  #pragma unroll 8
  for (int it = 0; it < NCOL / 4 / 256; ++it) {   // 64 iters
    const int c = (it << 8) + tid;
    float4 m = M4[c];
    float4 vv = V4[c];
    acc += __expf(-20.f * m.x) * vv.x + __expf(-20.f * m.y) * vv.y
         + __expf(-20.f * m.z) * vv.z + __expf(-20.f * m.w) * vv.w;
  }
  acc = wave_sum(acc);
  if ((tid & 63) == 0) sRed[tid >> 6] = acc;
  __syncthreads();
  if (tid == 0)
    u[row] = am / (sRed[0] + sRed[1] + sRed[2] + sRed[3] + EPSV);
}

// ---- k3a: streaming partial colsums of E^T u1 + speculative loss ----------
// Same geometry as k1a.
__global__ __launch_bounds__(256)
void k3a_partial(const float* __restrict__ M, const float* __restrict__ v,
                 const float* __restrict__ u, float* __restrict__ tPart,
                 float* __restrict__ eA) {
  const int tid = threadIdx.x, bid = blockIdx.x;
  const int band = bid >> 7, blk = bid & 127;
  const int chunk = tid & 127;
  const int part  = tid >> 7;
  const int col0  = (blk << 9) + (chunk << 2);
  const int r0l   = part << 5;              // local row offset in band

  __shared__ float sU[64];
  __shared__ float sCol[2 * 512];
  __shared__ float sRed[4];

  if (tid < 64) sU[tid] = u[(band << 6) + tid];
  __syncthreads();

  const float4 vv = *(const float4*)(v + col0);
  const float* Mb = M + (size_t)(band << 6) * NCOL;
  float4 cs = {0.f, 0.f, 0.f, 0.f};
  float lacc = 0.f;
  #pragma unroll 8
  for (int rl = r0l; rl < r0l + 32; ++rl) {
    float4 m = *(const float4*)(Mb + (size_t)rl * NCOL + col0);
    float e0 = __expf(-20.f * m.x), e1 = __expf(-20.f * m.y);
    float e2 = __expf(-20.f * m.z), e3 = __expf(-20.f * m.w);
    float us = sU[rl];
    cs.x = fmaf(e0, us, cs.x);
    cs.y = fmaf(e1, us, cs.y);
    cs.z = fmaf(e2, us, cs.z);
    cs.w = fmaf(e3, us, cs.w);
    lacc += us * (e0 * m.x * vv.x + e1 * m.y * vv.y
                + e2 * m.z * vv.z + e3 * m.w * vv.w);
  }
  *(float4*)(sCol + part * 512 + (chunk << 2)) = cs;
  lacc = wave_sum(lacc);
  if ((tid & 63) == 0) sRed[tid >> 6] = lacc;
  __syncthreads();
  if (tid < 128) {
    float4 a = *(const float4*)(sCol + (tid << 2));
    float4 b = *(const float4*)(sCol + 512 + (tid << 2));
    float4 t = {a.x + b.x, a.y + b.y, a.z + b.z, a.w + b.w};
    *(float4*)(tPart + (size_t)band * NCOL + (blk << 9) + (tid << 2)) = t;
  }
  if (tid == 0)
    atomicAdd(&eA[2], sRed[0] + sRed[1] + sRed[2] + sRed[3]);
}

// ---- k3b: t = reduce(partials) (stored for k5), err = sum|v*t - b| --------
__global__ __launch_bounds__(256)
void k3b_err(const float* __restrict__ tPart, const float* __restrict__ v,
             float* __restrict__ tArr, float* __restrict__ eA) {
  const int tid = threadIdx.x;
  const int gid = blockIdx.x * 256 + tid;
  const int col0 = gid << 2;
  const float bm = 1.0f / NCOL;
  __shared__ float sRed[4];

  float4 t = {0.f, 0.f, 0.f, 0.f};
  #pragma unroll
  for (int b = 0; b < BANDS; ++b) {
    float4 p = *(const float4*)(tPart + (size_t)b * NCOL + col0);
    t.x += p.x; t.y += p.y; t.z += p.z; t.w += p.w;
  }
  *(float4*)(tArr + col0) = t;
  float4 vv = *(const float4*)(v + col0);
  float pe = fabsf(vv.x * t.x - bm) + fabsf(vv.y * t.y - bm)
           + fabsf(vv.z * t.z - bm) + fabsf(vv.w * t.w - bm);
  pe = wave_sum(pe);
  if ((tid & 63) == 0) sRed[tid >> 6] = pe;
  __syncthreads();
  if (tid == 0)
    atomicAdd(&eA[0], sRed[0] + sRed[1] + sRed[2] + sRed[3]);
}

// ---- k4: decide ------------------------------------------------------------
__global__ void k4_decide(const float* __restrict__ eA, float* __restrict__ out,
                          int* __restrict__ done) {
  if (threadIdx.x == 0) {
    if (eA[0] <= 0.005f) { out[0] = 100.f * eA[2]; done[0] = 1; }
    else                 { out[0] = 0.f;           done[0] = 0; }
  }
}

// ---- k5: cooperative fallback (iters 2..100 + loss); exits when done -------
__global__ __launch_bounds__(1024)
void k5_fallback(const float* __restrict__ M, float* __restrict__ out,
                 float* __restrict__ v, float* __restrict__ u,
                 const float* __restrict__ tArr, float* __restrict__ eA,
                 const int* __restrict__ done) {
  if (done[0]) return;
  cg::grid_group grid = cg::this_grid();
  const int tid = threadIdx.x, bid = blockIdx.x;
  const float am = 1.0f / NROW, bm = 1.0f / NCOL, EPSV = 1e-16f;

  __shared__ float sU[NROW];
  __shared__ float sCol[16 * 256];
  __shared__ float sRedA[16], sRedB[16];

  const int chunk = tid & 63;
  const int part  = tid >> 6;
  const int col0  = (bid << 8) + (chunk << 2);
  const int r0    = part << 5;
  const int row0  = bid << 1;

  float tt = (tid < 256) ? tArr[(bid << 8) + tid] : 0.f;

  int cpt = 1;
  while (true) {
    if (tid < 256) v[(bid << 8) + tid] = bm / (tt + EPSV);
    grid.sync();
    cpt++;

    {
      const float4* M40 = (const float4*)M + (size_t)row0 * (NCOL / 4);
      const float4* M41 = (const float4*)M + (size_t)(row0 + 1) * (NCOL / 4);
      const float4* V4  = (const float4*)v;
      float ra = 0.f, rb = 0.f;
      #pragma unroll 4
      for (int it = 0; it < NCOL / 4 / 1024; ++it) {
        const int c = (it << 10) + tid;
        float4 vv = V4[c];
        float4 m0 = M40[c], m1 = M41[c];
        ra += __expf(-20.f * m0.x) * vv.x + __expf(-20.f * m0.y) * vv.y
            + __expf(-20.f * m0.z) * vv.z + __expf(-20.f * m0.w) * vv.w;
        rb += __expf(-20.f * m1.x) * vv.x + __expf(-20.f * m1.y) * vv.y
            + __expf(-20.f * m1.z) * vv.z + __expf(-20.f * m1.w) * vv.w;
      }
      ra = wave_sum(ra); rb = wave_sum(rb);
      if ((tid & 63) == 0) { sRedA[tid >> 6] = ra; sRedB[tid >> 6] = rb; }
      __syncthreads();
      if (tid < 2) {
        const float* sr = (tid == 0) ? sRedA : sRedB;
        float s = 0.f;
        #pragma unroll
        for (int w = 0; w < 16; ++w) s += sr[w];
        u[row0 + tid] = am / (s + EPSV);
      }
    }
    grid.sync();
    if (cpt >= 100) break;

    if (tid < NROW) sU[tid] = u[tid];
    __syncthreads();
    float4 cs = {0.f, 0.f, 0.f, 0.f};
    #pragma unroll 4
    for (int r = r0; r < r0 + 32; ++r) {
      float4 m = *(const float4*)(M + (size_t)r * NCOL + col0);
      float us = sU[r];
      cs.x = fmaf(__expf(-20.f * m.x), us, cs.x);
      cs.y = fmaf(__expf(-20.f * m.y), us, cs.y);
      cs.z = fmaf(__expf(-20.f * m.z), us, cs.z);
      cs.w = fmaf(__expf(-20.f * m.w), us, cs.w);
    }
    *(float4*)(sCol + part * 256 + (chunk << 2)) = cs;
    __syncthreads();
    if (tid < 256) {
      tt = 0.f;
      #pragma unroll
      for (int p = 0; p < 16; ++p) tt += sCol[p * 256 + tid];
    }

    if (cpt == 51) {
      float pe = (tid < 256) ? fabsf(v[(bid << 8) + tid] * tt - bm) : 0.f;
      pe = wave_sum(pe);
      __syncthreads();
      if ((tid & 63) == 0) sRedA[tid >> 6] = pe;
      __syncthreads();
      if (tid == 0) {
        float s = 0.f;
        #pragma unroll
        for (int w = 0; w < 16; ++w) s += sRedA[w];
        atomicAdd(&eA[1], s);
      }
      grid.sync();
      if (eA[1] <= 0.005f) break;
    }
  }

  __syncthreads();
  if (tid < NROW) sU[tid] = u[tid];
  __syncthreads();
  {
    const float4 vv = *(const float4*)(v + col0);
    float lacc = 0.f;
    #pragma unroll 4
    for (int r = r0; r < r0 + 32; ++r) {
      float4 m = *(const float4*)(M + (size_t)r * NCOL + col0);
      float us = sU[r];
      lacc += us * (__expf(-20.f * m.x) * m.x * vv.x
                  + __expf(-20.f * m.y) * m.y * vv.y
                  + __expf(-20.f * m.z) * m.z * vv.z
                  + __expf(-20.f * m.w) * m.w * vv.w);
    }
    lacc = wave_sum(lacc);
    if ((tid & 63) == 0) sRedA[tid >> 6] = lacc;
    __syncthreads();
    if (tid == 0) {
      float s = 0.f;
      #pragma unroll
      for (int w = 0; w < 16; ++w) s += sRedA[w];
      atomicAdd(out, 100.f * s);
    }
  }
}

extern "C" void kernel_launch(void* const* d_in, const int* in_sizes, int n_in,
                              void* d_out, int out_size, void* d_ws, size_t ws_size,
                              hipStream_t stream) {
  const float* M = (const float*)d_in[0];
  float* out = (float*)d_out;

  // ws: v | tArr | u | eA | done | tPart
  const size_t offV = 0;
  const size_t offT = offV + (size_t)NCOL * sizeof(float);      // 256 KB
  const size_t offU = offT + (size_t)NCOL * sizeof(float);      // 256 KB
  const size_t offE = offU + 4096;
  const size_t offD = offE + 256;
  const size_t offP = offD + 256;
  const size_t need = offP + (size_t)BANDS * NCOL * sizeof(float); // +2 MB
  if (ws_size < need) return;

  char* ws = (char*)d_ws;
  float* v     = (float*)(ws + offV);
  float* tArr  = (float*)(ws + offT);
  float* u     = (float*)(ws + offU);
  float* eA    = (float*)(ws + offE);
  int*   done  = (int*)(ws + offD);
  float* tPart = (float*)(ws + offP);

  k1a_partial<<<dim3(1024), dim3(256), 0, stream>>>(M, tPart, eA);
  k1b_v1     <<<dim3(64),   dim3(256), 0, stream>>>(tPart, v);
  k2_rowdot  <<<dim3(512),  dim3(256), 0, stream>>>(M, v, u);
  k3a_partial<<<dim3(1024), dim3(256), 0, stream>>>(M, v, u, tPart, eA);
  k3b_err    <<<dim3(64),   dim3(256), 0, stream>>>(tPart, v, tArr, eA);
  k4_decide  <<<dim3(1),    dim3(64),  0, stream>>>(eA, out, done);

  void* args[] = { (void*)&M, (void*)&out, (void*)&v, (void*)&u,
                   (void*)&tArr, (void*)&eA, (void*)&done };
  hipLaunchCooperativeKernel((void*)k5_fallback, dim3(256), dim3(1024),
                             args, 0, stream);
}